// Round 1
// baseline (211.789 us; speedup 1.0000x reference)
//
#include <hip/hip_runtime.h>
#include <hip/hip_cooperative_groups.h>
#include <math.h>

namespace cg = cooperative_groups;

// Problem constants: B=256, T=1024, F=64, Z=32, H=512
#define NB 256
#define NT 1024
#define NF 64
#define NZ 32
#define NH 512
#define K1 96   // F + Z

// Algebraic reduction (carried from previous rounds): reference returns h2
// after the FIRST scan step (time index T-1) with zero initial h/c:
//   - W_hh1/W_hh2 and the f-gate are dead
//   - c = sigmoid(i)*tanh(g); h = sigmoid(o)*tanh(c)
//   - out[b] = sum_j h2[b,j]*W_lin[j] + b_lin[0]
//
// This round: single cooperative kernel (3 dispatches -> 1).
//   Phase 1: per-block LDS staging of xin (input[:,T-1,:] ++ z) directly from
//            global (k_prep + xin4 workspace eliminated), layer-1 cell for
//            this block's 2 hidden units, packed h1 store to workspace.
//   grid.sync()  (device-scope fence -> cross-XCD h1p visibility)
//   Phase 2: layer-2 cell (K=512 split over 4 waves) + linear, atomicAdd out.
//
// h1p layout (workspace): [128][256] float4 — h1[j][b] packed 4-consecutive-j
// per lane: float index (j>>2)*(NB*4) + bt*4 + (j&3).

__device__ __forceinline__ float sigmoidf_(float x) {
    return 1.0f / (1.0f + __expf(-x));
}

// grid 1024 x 256: btb = blockIdx>>8 (batch quarter), g = blockIdx&255
// (unit-group of 2 units). Same-g replicas (x, x+256, ...) are congruent
// mod 8 -> land on the same XCD -> weight rows stay L2-local.
// __launch_bounds__(256,4): 4 waves/EU = 16 waves/CU = 4 blocks/CU, the
// exact co-residency needed for cooperative launch (1024 blocks / 256 CU).
__global__ __launch_bounds__(256, 4) void k_fused(
    const float* __restrict__ input, const float* __restrict__ z,
    const float* __restrict__ W_ih1, const float* __restrict__ b_ih1,
    const float* __restrict__ b_hh1,
    const float* __restrict__ W_ih2, const float* __restrict__ b_ih2,
    const float* __restrict__ b_hh2,
    const float* __restrict__ W_lin, const float* __restrict__ b_lin,
    float* __restrict__ h1p, float* __restrict__ out)
{
    const int tid  = threadIdx.x;
    const int lane = tid & 63;
    const int wv   = __builtin_amdgcn_readfirstlane(tid >> 6); // 0..3
    const int btb  = blockIdx.x >> 8;      // 0..3
    const int g    = blockIdx.x & 255;     // unit-group (2 units)
    const int bt   = btb * 64 + lane;
    const int j0   = 2 * g;

    __shared__ float4 xin[24][64];         // 24 KB: xin[k4][local_batch]
    __shared__ float  red[4][6][64];       //  6 KB: cross-wave partial reduce

    // ---- Phase 1a: stage xin for this block's 64 batches -------------------
    {
        const int lb  = tid >> 2;          // local batch 0..63
        const int q   = tid & 3;           // quarter
        const int gbt = btb * 64 + lb;
        // input[gbt, T-1, :] as float4 (64 floats = 16 float4)
        const float4* __restrict__ in4 =
            (const float4*)input + (size_t)gbt * (NT * NF / 4) + ((NT - 1) * NF / 4);
        // z[gbt, :] as float4 (32 floats = 8 float4)
        const float4* __restrict__ z4 =
            (const float4*)z + (size_t)gbt * (NZ / 4);
        #pragma unroll
        for (int i = 0; i < 4; ++i) {
            int k4 = q + i * 4;            // 0..15
            xin[k4][lb] = in4[k4];         // 4 consecutive tids read one line
        }
        #pragma unroll
        for (int i = 0; i < 2; ++i) {
            int k4 = q + i * 4;            // 0..7
            xin[16 + k4][lb] = z4[k4];
        }
        // out init (one g-replica per batch quarter); phase-2 atomics are
        // separated from this plain store by grid.sync's device fence.
        if (g == 0 && tid < 64) out[btb * 64 + tid] = b_lin[0];
    }
    __syncthreads();

    // ---- Phase 1b: layer-1 cell, 2 units, K=96 split 4 ways over waves -----
    {
        const float* __restrict__ w[6];
        #pragma unroll
        for (int u = 0; u < 2; ++u) {
            w[u * 3 + 0] = W_ih1 + (size_t)(j0 + u) * K1;          // i-gate
            w[u * 3 + 1] = W_ih1 + (size_t)(1024 + j0 + u) * K1;   // g-gate
            w[u * 3 + 2] = W_ih1 + (size_t)(1536 + j0 + u) * K1;   // o-gate
        }
        float acc[6] = {0, 0, 0, 0, 0, 0};
        #pragma unroll
        for (int i = 0; i < 6; ++i) {
            int k4 = wv * 6 + i;           // wave-uniform k4
            float4 h = xin[k4][lane];
            #pragma unroll
            for (int r = 0; r < 6; ++r) {
                const float* wr = w[r] + k4 * 4;   // wave-uniform -> s_load
                acc[r] = fmaf(wr[0], h.x, acc[r]);
                acc[r] = fmaf(wr[1], h.y, acc[r]);
                acc[r] = fmaf(wr[2], h.z, acc[r]);
                acc[r] = fmaf(wr[3], h.w, acc[r]);
            }
        }
        #pragma unroll
        for (int r = 0; r < 6; ++r) red[wv][r][lane] = acc[r];
    }
    __syncthreads();

    if (wv == 0) {
        float s[6];
        #pragma unroll
        for (int r = 0; r < 6; ++r)
            s[r] = red[0][r][lane] + red[1][r][lane] +
                   red[2][r][lane] + red[3][r][lane];
        float hu[2];
        #pragma unroll
        for (int u = 0; u < 2; ++u) {
            int j = j0 + u;
            float gi = s[u * 3 + 0] + b_ih1[j]        + b_hh1[j];
            float gg = s[u * 3 + 1] + b_ih1[1024 + j] + b_hh1[1024 + j];
            float go = s[u * 3 + 2] + b_ih1[1536 + j] + b_hh1[1536 + j];
            float c1 = sigmoidf_(gi) * tanhf(gg);
            hu[u] = sigmoidf_(go) * tanhf(c1);
        }
        // packed store: j0 even -> 8B-aligned float2
        *(float2*)(h1p + (j0 >> 2) * (NB * 4) + bt * 4 + (j0 & 3)) =
            make_float2(hu[0], hu[1]);
    }

    // ---- grid-wide barrier: h1p produced by all 256 g-blocks per btb -------
    cg::this_grid().sync();

    // ---- Phase 2: layer-2 cell (K=512 over 4 waves) + linear ---------------
    {
        const float4* __restrict__ hv = (const float4*)h1p + bt;
        const float* __restrict__ w[6];
        #pragma unroll
        for (int u = 0; u < 2; ++u) {
            w[u * 3 + 0] = W_ih2 + (size_t)(j0 + u) * NH;
            w[u * 3 + 1] = W_ih2 + (size_t)(1024 + j0 + u) * NH;
            w[u * 3 + 2] = W_ih2 + (size_t)(1536 + j0 + u) * NH;
        }
        float acc[6] = {0, 0, 0, 0, 0, 0};
        const int k4base = wv * 32;        // 32 float4 iters = 128 K per wave
        #pragma unroll 8
        for (int k4i = 0; k4i < 32; ++k4i) {
            int k4 = k4base + k4i;
            float4 h = hv[k4 * NB];        // coalesced 16B/lane, L2-resident
            #pragma unroll
            for (int r = 0; r < 6; ++r) {
                const float* wr = w[r] + k4 * 4;   // wave-uniform -> s_load
                acc[r] = fmaf(wr[0], h.x, acc[r]);
                acc[r] = fmaf(wr[1], h.y, acc[r]);
                acc[r] = fmaf(wr[2], h.z, acc[r]);
                acc[r] = fmaf(wr[3], h.w, acc[r]);
            }
        }
        #pragma unroll
        for (int r = 0; r < 6; ++r) red[wv][r][lane] = acc[r];
        __syncthreads();

        if (wv == 0) {
            float s[6];
            #pragma unroll
            for (int r = 0; r < 6; ++r)
                s[r] = red[0][r][lane] + red[1][r][lane] +
                       red[2][r][lane] + red[3][r][lane];
            float partial = 0.0f;
            #pragma unroll
            for (int u = 0; u < 2; ++u) {
                int j = j0 + u;
                float gi = s[u * 3 + 0] + b_ih2[j]        + b_hh2[j];
                float gg = s[u * 3 + 1] + b_ih2[1024 + j] + b_hh2[1024 + j];
                float go = s[u * 3 + 2] + b_ih2[1536 + j] + b_hh2[1536 + j];
                float c2 = sigmoidf_(gi) * tanhf(gg);
                float h2 = sigmoidf_(go) * tanhf(c2);
                partial  = fmaf(h2, W_lin[j], partial);
            }
            atomicAdd(out + bt, partial);
        }
    }
}

// ---------------------------------------------------------------------------
extern "C" void kernel_launch(void* const* d_in, const int* in_sizes, int n_in,
                              void* d_out, int out_size, void* d_ws, size_t ws_size,
                              hipStream_t stream) {
    const float* input = (const float*)d_in[0];
    const float* z     = (const float*)d_in[1];
    // d_in[2]=h0, d_in[3]=c0 zeros -> unused; d_in[5]=W_hh1, d_in[9]=W_hh2 dead
    const float* W_ih1 = (const float*)d_in[4];
    const float* b_ih1 = (const float*)d_in[6];
    const float* b_hh1 = (const float*)d_in[7];
    const float* W_ih2 = (const float*)d_in[8];
    const float* b_ih2 = (const float*)d_in[10];
    const float* b_hh2 = (const float*)d_in[11];
    const float* W_lin = (const float*)d_in[12];
    const float* b_lin = (const float*)d_in[13];

    float* out = (float*)d_out;            // 256 floats
    float* h1p = (float*)d_ws;             // 128*256*4 floats (512 KB)

    void* args[] = {
        (void*)&input, (void*)&z,
        (void*)&W_ih1, (void*)&b_ih1, (void*)&b_hh1,
        (void*)&W_ih2, (void*)&b_ih2, (void*)&b_hh2,
        (void*)&W_lin, (void*)&b_lin,
        (void*)&h1p,   (void*)&out
    };
    hipLaunchCooperativeKernel((void*)k_fused, dim3(1024), dim3(256),
                               args, 0, stream);
}

// Round 2
// 143.603 us; speedup vs baseline: 1.4748x; 1.4748x over previous
//
#include <hip/hip_runtime.h>
#include <math.h>

// Problem constants: B=256, T=1024, F=64, Z=32, H=512
#define NB 256
#define NT 1024
#define NF 64
#define NZ 32
#define NH 512
#define K1 96   // F + Z

// Algebraic reduction (carried from round 0): reference returns h2 after the
// FIRST scan step (time index T-1) with zero initial h/c:
//   - W_hh1/W_hh2 and the f-gate are dead
//   - c = sigmoid(i)*tanh(g); h = sigmoid(o)*tanh(c)
//   - out[b] = sum_j h2[b,j]*W_lin[j] + b_lin[0]
//
// Round-1 lesson (measured): cooperative grid.sync() over 1024 blocks costs
// ~50 us on this 8-XCD part — far more than the dispatch boundaries it
// replaces. Structure here: TWO stream-ordered kernels.
//   k_lstm1f: per-block LDS staging of xin (input[:,T-1,:] ++ z) directly
//             from global (k_prep + xin4 workspace eliminated), layer-1
//             cell, packed h1 store. Also initializes out = b_lin.
//   k_lstm2 : unchanged from the 145.9 us baseline (layer-2 + linear).
//
// h1p layout (workspace): [128][256] float4 — h1[j][b] packed 4-consecutive-j
// per lane: float index (j>>2)*(NB*4) + bt*4 + (j&3).

__device__ __forceinline__ float sigmoidf_(float x) {
    return 1.0f / (1.0f + __expf(-x));
}

// ---------------------------------------------------------------------------
// layer 1 (with fused input staging): h1 = lstm_cell(xin) with h=c=0.
// grid 1024 x 64 (1 wave/block): btb = blockIdx>>8 (same-g replicas land on
// the same XCD: x and x+256 are congruent mod 8), group g = blockIdx&255.
// Each wave: 2 hidden units (6 weight rows), K=96 as 24 float4 iters.
// ---------------------------------------------------------------------------
__global__ __launch_bounds__(64) void k_lstm1f(
    const float* __restrict__ input, const float* __restrict__ z,
    const float* __restrict__ W_ih1, const float* __restrict__ b_ih1,
    const float* __restrict__ b_hh1, const float* __restrict__ b_lin,
    float* __restrict__ h1p, float* __restrict__ out)
{
    const int lane = threadIdx.x;
    const int btb  = blockIdx.x >> 8;      // 0..3
    const int g    = blockIdx.x & 255;     // unit-group (2 units)
    const int bt   = btb * 64 + lane;
    const int j0   = 2 * g;

    __shared__ float4 xin[24][64];         // 24 KB: xin[k4][local_batch]

    // ---- stage xin for this block's 64 batches (lane = own batch) ----------
    {
        // input[bt, T-1, :] : 16 float4, contiguous 256B per lane
        const float4* __restrict__ in4 =
            (const float4*)input + (size_t)bt * (NT * NF / 4) + ((NT - 1) * NF / 4);
        const float4* __restrict__ z4 =
            (const float4*)z + (size_t)bt * (NZ / 4);
        #pragma unroll
        for (int k4 = 0; k4 < 16; ++k4) xin[k4][lane] = in4[k4];
        #pragma unroll
        for (int k4 = 0; k4 < 8; ++k4)  xin[16 + k4][lane] = z4[k4];
        // out init (one g-replica per batch quarter); k_lstm2's atomics are
        // ordered after this by stream-serialized dispatch.
        if (g == 0) out[bt] = b_lin[0];
    }
    __syncthreads();   // single wave: compiles to a waitcnt, cheap

    // ---- layer-1 cell: 2 units, 6 weight rows, K=96 ------------------------
    const float* __restrict__ w[6];
    #pragma unroll
    for (int u = 0; u < 2; ++u) {
        w[u * 3 + 0] = W_ih1 + (size_t)(j0 + u) * K1;          // i-gate
        w[u * 3 + 1] = W_ih1 + (size_t)(1024 + j0 + u) * K1;   // g-gate
        w[u * 3 + 2] = W_ih1 + (size_t)(1536 + j0 + u) * K1;   // o-gate
    }

    float acc[6] = {0, 0, 0, 0, 0, 0};
    #pragma unroll
    for (int k4 = 0; k4 < 24; ++k4) {
        float4 h = xin[k4][lane];          // ds_read_b128, conflict-free
        #pragma unroll
        for (int r = 0; r < 6; ++r) {
            const float* wr = w[r] + k4 * 4;   // wave-uniform -> s_load
            acc[r] = fmaf(wr[0], h.x, acc[r]);
            acc[r] = fmaf(wr[1], h.y, acc[r]);
            acc[r] = fmaf(wr[2], h.z, acc[r]);
            acc[r] = fmaf(wr[3], h.w, acc[r]);
        }
    }

    float hu[2];
    #pragma unroll
    for (int u = 0; u < 2; ++u) {
        int j = j0 + u;
        float gi = acc[u * 3 + 0] + b_ih1[j]        + b_hh1[j];
        float gg = acc[u * 3 + 1] + b_ih1[1024 + j] + b_hh1[1024 + j];
        float go = acc[u * 3 + 2] + b_ih1[1536 + j] + b_hh1[1536 + j];
        float c1 = sigmoidf_(gi) * tanhf(gg);
        hu[u] = sigmoidf_(go) * tanhf(c1);
    }
    // packed store: float index (j0>>2)*1024 + bt*4 + (j0&3); j0 even -> 8B aligned
    *(float2*)(h1p + (j0 >> 2) * (NB * 4) + bt * 4 + (j0 & 3)) =
        make_float2(hu[0], hu[1]);
}

// ---------------------------------------------------------------------------
// layer 2 + linear: h2 = lstm_cell(h1); out[bt] += h2 . W_lin  (atomic).
// grid 1024 x 256 (4 waves/block, 16 waves/CU): block = (btb = blockIdx>>8,
// group g = blockIdx&255 covering 2 units / 6 rows). Wave wv takes K-chunk
// [wv*128, wv*128+128); partials reduced via LDS; wave 0 does the epilogue.
// (Byte-identical to the 145.9 us baseline version.)
// ---------------------------------------------------------------------------
__global__ __launch_bounds__(256) void k_lstm2(
    const float* __restrict__ W_ih2, const float* __restrict__ b_ih2,
    const float* __restrict__ b_hh2, const float* __restrict__ W_lin,
    const float* __restrict__ h1p, float* __restrict__ out)
{
    const int tid  = threadIdx.x;
    const int lane = tid & 63;
    const int wv   = __builtin_amdgcn_readfirstlane(tid >> 6); // 0..3
    const int btb  = blockIdx.x >> 8;      // 0..3
    const int g    = blockIdx.x & 255;     // unit-group (2 units)
    const int bt   = btb * 64 + lane;
    const int j0   = 2 * g;

    const float4* __restrict__ hv = (const float4*)h1p + bt;

    const float* __restrict__ w[6];
    #pragma unroll
    for (int u = 0; u < 2; ++u) {
        w[u * 3 + 0] = W_ih2 + (size_t)(j0 + u) * NH;
        w[u * 3 + 1] = W_ih2 + (size_t)(1024 + j0 + u) * NH;
        w[u * 3 + 2] = W_ih2 + (size_t)(1536 + j0 + u) * NH;
    }

    float acc[6] = {0, 0, 0, 0, 0, 0};
    const int k4base = wv * 32;            // 32 float4 iters = 128 K
    #pragma unroll 8
    for (int k4i = 0; k4i < 32; ++k4i) {
        int k4 = k4base + k4i;
        float4 h = hv[k4 * NB];            // coalesced 16B/lane
        #pragma unroll
        for (int r = 0; r < 6; ++r) {
            const float* wr = w[r] + k4 * 4;   // wave-uniform -> s_load
            acc[r] = fmaf(wr[0], h.x, acc[r]);
            acc[r] = fmaf(wr[1], h.y, acc[r]);
            acc[r] = fmaf(wr[2], h.z, acc[r]);
            acc[r] = fmaf(wr[3], h.w, acc[r]);
        }
    }

    __shared__ float red[4][6][64];
    #pragma unroll
    for (int r = 0; r < 6; ++r) red[wv][r][lane] = acc[r];
    __syncthreads();

    if (wv == 0) {
        float s[6];
        #pragma unroll
        for (int r = 0; r < 6; ++r)
            s[r] = red[0][r][lane] + red[1][r][lane] +
                   red[2][r][lane] + red[3][r][lane];
        float partial = 0.0f;
        #pragma unroll
        for (int u = 0; u < 2; ++u) {
            int j = j0 + u;
            float gi = s[u * 3 + 0] + b_ih2[j]        + b_hh2[j];
            float gg = s[u * 3 + 1] + b_ih2[1024 + j] + b_hh2[1024 + j];
            float go = s[u * 3 + 2] + b_ih2[1536 + j] + b_hh2[1536 + j];
            float c2 = sigmoidf_(gi) * tanhf(gg);
            float h2 = sigmoidf_(go) * tanhf(c2);
            partial  = fmaf(h2, W_lin[j], partial);
        }
        atomicAdd(out + bt, partial);
    }
}

// ---------------------------------------------------------------------------
extern "C" void kernel_launch(void* const* d_in, const int* in_sizes, int n_in,
                              void* d_out, int out_size, void* d_ws, size_t ws_size,
                              hipStream_t stream) {
    const float* input = (const float*)d_in[0];
    const float* z     = (const float*)d_in[1];
    // d_in[2]=h0, d_in[3]=c0 zeros -> unused; d_in[5]=W_hh1, d_in[9]=W_hh2 dead
    const float* W_ih1 = (const float*)d_in[4];
    const float* b_ih1 = (const float*)d_in[6];
    const float* b_hh1 = (const float*)d_in[7];
    const float* W_ih2 = (const float*)d_in[8];
    const float* b_ih2 = (const float*)d_in[10];
    const float* b_hh2 = (const float*)d_in[11];
    const float* W_lin = (const float*)d_in[12];
    const float* b_lin = (const float*)d_in[13];

    float* out = (float*)d_out;            // 256 floats
    float* h1p = (float*)d_ws;             // 128*256*4 floats (512 KB)

    k_lstm1f<<<1024,  64, 0, stream>>>(input, z, W_ih1, b_ih1, b_hh1, b_lin,
                                       h1p, out);
    k_lstm2 <<<1024, 256, 0, stream>>>(W_ih2, b_ih2, b_hh2, W_lin, h1p, out);
}